// Round 1
// baseline (795.606 us; speedup 1.0000x reference)
//
#include <hip/hip_runtime.h>
#include <stdint.h>

#define SEQ_LEN 4096
#define N_HEADS 16
#define H_DIM 64
#define E_DIM 1024
#define NBH 32            // BS * N_HEADS
#define M_TOT 8192        // BS * SEQ_LEN

typedef __attribute__((ext_vector_type(8))) short short8;
typedef __attribute__((ext_vector_type(4))) float f32x4;
typedef __attribute__((ext_vector_type(4))) unsigned short u16x4;

__device__ __forceinline__ unsigned short f2bf(float f) {
  union { float f; uint32_t u; } c; c.f = f;
  uint32_t u = c.u;
  u += 0x7FFFu + ((u >> 16) & 1u);   // round-to-nearest-even
  return (unsigned short)(u >> 16);
}

__device__ __forceinline__ f32x4 mfma16(short8 a, short8 b, f32x4 c) {
  return __builtin_amdgcn_mfma_f32_16x16x32_bf16(a, b, c, 0, 0, 0);
}

// ---------------- prep kernels ----------------

__global__ __launch_bounds__(256) void cast_x_kernel(const float* __restrict__ x,
                                                     unsigned short* __restrict__ xb) {
  const int i = (blockIdx.x * 256 + threadIdx.x) * 4;
  const f32x4 v = *(const f32x4*)(x + i);
  u16x4 o;
  #pragma unroll
  for (int j = 0; j < 4; j++) o[j] = f2bf(v[j]);
  *(u16x4*)(xb + i) = o;
}

// W [K][N] fp32 -> Wt [N][K] bf16 ; z selects Wq/Wk/Wv/Wo
__global__ __launch_bounds__(256) void transpose_w_kernel(
    const float* __restrict__ Wq, const float* __restrict__ Wk,
    const float* __restrict__ Wv, const float* __restrict__ Wo,
    unsigned short* __restrict__ Wqkvt, unsigned short* __restrict__ Wot) {
  __shared__ float tile[32][33];
  const int z = blockIdx.z;
  const float* src = (z == 0) ? Wq : (z == 1) ? Wk : (z == 2) ? Wv : Wo;
  unsigned short* dst = (z < 3) ? (Wqkvt + (size_t)z * E_DIM * E_DIM) : Wot;
  const int n0 = blockIdx.x * 32, k0 = blockIdx.y * 32;
  const int tx = threadIdx.x, ty = threadIdx.y;
  #pragma unroll
  for (int i = 0; i < 4; i++)
    tile[ty + i * 8][tx] = src[(size_t)(k0 + ty + i * 8) * E_DIM + n0 + tx];
  __syncthreads();
  #pragma unroll
  for (int i = 0; i < 4; i++)
    dst[(size_t)(n0 + ty + i * 8) * E_DIM + k0 + tx] = f2bf(tile[tx][ty + i * 8]);
}

// mask int32 [L][L] -> bitmask uint64 [L][L/64]
__global__ __launch_bounds__(256) void pack_mask_kernel(const int* __restrict__ mask,
                                                        unsigned long long* __restrict__ mw) {
  const int e = blockIdx.x * 256 + threadIdx.x;
  const int bit = mask[e] != 0;
  const unsigned long long bal = __ballot(bit);
  if ((threadIdx.x & 63) == 0) mw[e >> 6] = bal;
}

// ---------------- GEMM: C[m][n] = sum_k A[m][k] * Bt[n][k] (+bias) ----------------
// MODE 0: fused QKV epilogue (scatter Q,K [bh][l][d], V transposed [bh][d][l], bf16)
// MODE 1: fp32 output + bias (b0)
#define LDT 40   // padded LDS row (elems) for 32-wide K tiles

template<int MODE>
__global__ __launch_bounds__(256) void gemm_kernel(
    const unsigned short* __restrict__ A,
    const unsigned short* __restrict__ Bt,
    const float* __restrict__ b0, const float* __restrict__ b1, const float* __restrict__ b2,
    unsigned short* __restrict__ Qo, unsigned short* __restrict__ Ko,
    unsigned short* __restrict__ Vto, float* __restrict__ Co)
{
  __shared__ unsigned short As[128 * LDT];
  __shared__ unsigned short Bs[128 * LDT];
  const int tid = threadIdx.x;
  const int lane = tid & 63, wid = tid >> 6;
  const int l15 = lane & 15, g = lane >> 4;
  const int bm = blockIdx.x * 128, bn = blockIdx.y * 128;
  const int wm = (wid >> 1) * 64, wn = (wid & 1) * 64;

  const int srow = tid >> 2, scol = (tid & 3) * 8;
  const unsigned short* ap0 = A  + (size_t)(bm + srow) * E_DIM + scol;
  const unsigned short* ap1 = ap0 + (size_t)64 * E_DIM;
  const unsigned short* bp0 = Bt + (size_t)(bn + srow) * E_DIM + scol;
  const unsigned short* bp1 = bp0 + (size_t)64 * E_DIM;
  unsigned short* aw0 = As + srow * LDT + scol;
  unsigned short* aw1 = aw0 + 64 * LDT;
  unsigned short* bw0 = Bs + srow * LDT + scol;
  unsigned short* bw1 = bw0 + 64 * LDT;

  f32x4 acc[4][4] = {};

  for (int k0 = 0; k0 < E_DIM; k0 += 32) {
    const short8 ra0 = *(const short8*)(ap0 + k0);
    const short8 ra1 = *(const short8*)(ap1 + k0);
    const short8 rb0 = *(const short8*)(bp0 + k0);
    const short8 rb1 = *(const short8*)(bp1 + k0);
    __syncthreads();
    *(short8*)aw0 = ra0;  *(short8*)aw1 = ra1;
    *(short8*)bw0 = rb0;  *(short8*)bw1 = rb1;
    __syncthreads();
    short8 af[4], bf[4];
    #pragma unroll
    for (int i = 0; i < 4; i++)
      af[i] = *(const short8*)(As + (wm + i * 16 + l15) * LDT + g * 8);
    #pragma unroll
    for (int j = 0; j < 4; j++)
      bf[j] = *(const short8*)(Bs + (wn + j * 16 + l15) * LDT + g * 8);
    #pragma unroll
    for (int i = 0; i < 4; i++)
      #pragma unroll
      for (int j = 0; j < 4; j++)
        acc[i][j] = mfma16(af[i], bf[j], acc[i][j]);
  }

  #pragma unroll
  for (int i = 0; i < 4; i++) {
    #pragma unroll
    for (int j = 0; j < 4; j++) {
      const int n  = bn + wn + j * 16 + l15;
      const int m0 = bm + wm + i * 16 + g * 4;
      if (MODE == 1) {
        const float bias = b0[n];
        #pragma unroll
        for (int r = 0; r < 4; r++)
          Co[(size_t)(m0 + r) * E_DIM + n] = acc[i][j][r] + bias;
      } else {
        const int sec = n >> 10, nn = n & 1023;
        const int h = nn >> 6, d = nn & 63;
        const float bias = (sec == 0 ? b0 : sec == 1 ? b1 : b2)[nn];
        if (sec == 2) {
          u16x4 vv;
          #pragma unroll
          for (int r = 0; r < 4; r++) vv[r] = f2bf(acc[i][j][r] + bias);
          const int b = m0 >> 12, l0 = m0 & 4095;
          *(u16x4*)(Vto + ((size_t)(b * N_HEADS + h) * H_DIM + d) * SEQ_LEN + l0) = vv;
        } else {
          unsigned short* dst = (sec == 0) ? Qo : Ko;
          #pragma unroll
          for (int r = 0; r < 4; r++) {
            const int m = m0 + r;
            const int b = m >> 12, l = m & 4095;
            dst[((size_t)(b * N_HEADS + h) * SEQ_LEN + l) * H_DIM + d] = f2bf(acc[i][j][r] + bias);
          }
        }
      }
    }
  }
}

// ---------------- flash attention ----------------
// grid (SEQ_LEN/128, NBH), 256 threads (4 waves x 32 q-rows)
#define LDK 72    // Ks/Qs padded row (elems), 64 cols
#define LDV 136   // Vts padded row (elems), 128 cols
#define LDP 72    // per-wave P row (elems), 64 cols (half-tile)

__global__ __launch_bounds__(256) void attn_kernel(
    const unsigned short* __restrict__ Qg, const unsigned short* __restrict__ Kg,
    const unsigned short* __restrict__ Vg, const unsigned long long* __restrict__ mw,
    unsigned short* __restrict__ Ob)
{
  __shared__ unsigned short Ks[128 * LDK];            // 18432 B
  __shared__ unsigned short Vts[64 * LDV];            // 17408 B
  __shared__ unsigned short PQ[4 * 32 * LDP];         // 18432 B (Qs union Ps)
  const int tid = threadIdx.x, lane = tid & 63, wid = tid >> 6;
  const int l15 = lane & 15, g = lane >> 4;
  const int q0 = blockIdx.x * 128, bh = blockIdx.y;
  const unsigned short* Qp = Qg + ((size_t)bh * SEQ_LEN + q0) * H_DIM;
  const unsigned short* Kp = Kg + (size_t)bh * SEQ_LEN * H_DIM;
  const unsigned short* Vp = Vg + (size_t)bh * H_DIM * SEQ_LEN;
  const int wq = wid * 32;

  // stage Q into PQ ([128][LDK]) and load per-wave Q fragments
  unsigned short* Qs = PQ;
  #pragma unroll
  for (int it = 0; it < 4; it++) {
    const int C = it * 256 + tid;
    const int row = C >> 3, c = (C & 7) * 8;
    *(short8*)(Qs + row * LDK + c) = *(const short8*)(Qp + row * H_DIM + c);
  }
  __syncthreads();
  short8 qf[2][2];
  #pragma unroll
  for (int i = 0; i < 2; i++)
    #pragma unroll
    for (int ks = 0; ks < 2; ks++)
      qf[i][ks] = *(const short8*)(Qs + (wq + i * 16 + l15) * LDK + ks * 32 + g * 8);
  __syncthreads();

  float m_run[2][4], l_run[2][4];
  #pragma unroll
  for (int i = 0; i < 2; i++)
    #pragma unroll
    for (int r = 0; r < 4; r++) { m_run[i][r] = -1e30f; l_run[i][r] = 0.f; }
  f32x4 acc_o[2][4] = {};

  unsigned short* Ps = PQ + wid * (32 * LDP);

  for (int kt = 0; kt < SEQ_LEN / 128; kt++) {
    // reg-stage K,Vt tiles
    short8 rk[4], rv[4];
    int rowk[4], ck[4], rowv[4], cv[4];
    #pragma unroll
    for (int it = 0; it < 4; it++) {
      const int C = it * 256 + tid;
      rowk[it] = C >> 3; ck[it] = (C & 7) * 8;
      rk[it] = *(const short8*)(Kp + (size_t)(kt * 128 + rowk[it]) * H_DIM + ck[it]);
      rowv[it] = C >> 4; cv[it] = (C & 15) * 8;
      rv[it] = *(const short8*)(Vp + (size_t)rowv[it] * SEQ_LEN + kt * 128 + cv[it]);
    }
    __syncthreads();
    #pragma unroll
    for (int it = 0; it < 4; it++) {
      *(short8*)(Ks + rowk[it] * LDK + ck[it]) = rk[it];
      *(short8*)(Vts + rowv[it] * LDV + cv[it]) = rv[it];
    }
    __syncthreads();

    // S = Q K^T  (per wave: 32 q-rows x 128 keys)
    f32x4 s[2][8];
    #pragma unroll
    for (int j = 0; j < 8; j++) {
      const short8 kf0 = *(const short8*)(Ks + (j * 16 + l15) * LDK + g * 8);
      const short8 kf1 = *(const short8*)(Ks + (j * 16 + l15) * LDK + 32 + g * 8);
      #pragma unroll
      for (int i = 0; i < 2; i++) {
        f32x4 z = {0.f, 0.f, 0.f, 0.f};
        z = mfma16(qf[i][0], kf0, z);
        s[i][j] = mfma16(qf[i][1], kf1, z);
      }
    }

    // scale + mask + online softmax
    #pragma unroll
    for (int i = 0; i < 2; i++) {
      unsigned long long w0[4], w1[4];
      #pragma unroll
      for (int r = 0; r < 4; r++) {
        const unsigned long long* mp =
            mw + (size_t)(q0 + wq + i * 16 + g * 4 + r) * (SEQ_LEN / 64) + kt * 2;
        w0[r] = mp[0]; w1[r] = mp[1];
      }
      float tm[4] = {-1e30f, -1e30f, -1e30f, -1e30f};
      #pragma unroll
      for (int j = 0; j < 8; j++) {
        const int kb = j * 16 + l15;
        #pragma unroll
        for (int r = 0; r < 4; r++) {
          const unsigned long long w = (kb < 64) ? w0[r] : w1[r];
          const float sv = s[i][j][r] * 0.125f + (((w >> (kb & 63)) & 1ull) ? -10000.f : 0.f);
          s[i][j][r] = sv;
          tm[r] = fmaxf(tm[r], sv);
        }
      }
      #pragma unroll
      for (int r = 0; r < 4; r++) {
        #pragma unroll
        for (int off = 1; off < 16; off <<= 1)
          tm[r] = fmaxf(tm[r], __shfl_xor(tm[r], off));
        const float mn = fmaxf(m_run[i][r], tm[r]);
        const float corr = __expf(m_run[i][r] - mn);
        m_run[i][r] = mn;
        l_run[i][r] *= corr;
        #pragma unroll
        for (int dsub = 0; dsub < 4; dsub++) acc_o[i][dsub][r] *= corr;
      }
      float rs[4] = {0.f, 0.f, 0.f, 0.f};
      #pragma unroll
      for (int j = 0; j < 8; j++)
        #pragma unroll
        for (int r = 0; r < 4; r++) {
          const float p = __expf(s[i][j][r] - m_run[i][r]);
          s[i][j][r] = p;
          rs[r] += p;
        }
      #pragma unroll
      for (int r = 0; r < 4; r++) {
        #pragma unroll
        for (int off = 1; off < 16; off <<= 1)
          rs[r] += __shfl_xor(rs[r], off);
        l_run[i][r] += rs[r];
      }
    }

    // O += P V, in two half-tiles of 64 keys through per-wave LDS P buffer
    #pragma unroll
    for (int half = 0; half < 2; half++) {
      #pragma unroll
      for (int i = 0; i < 2; i++)
        #pragma unroll
        for (int jj = 0; jj < 4; jj++)
          #pragma unroll
          for (int r = 0; r < 4; r++)
            Ps[(i * 16 + g * 4 + r) * LDP + jj * 16 + l15] = f2bf(s[i][half * 4 + jj][r]);
      #pragma unroll
      for (int kq = 0; kq < 2; kq++) {
        short8 pf[2];
        #pragma unroll
        for (int i = 0; i < 2; i++)
          pf[i] = *(const short8*)(Ps + (i * 16 + l15) * LDP + kq * 32 + g * 8);
        #pragma unroll
        for (int dsub = 0; dsub < 4; dsub++) {
          const short8 vf =
              *(const short8*)(Vts + (dsub * 16 + l15) * LDV + half * 64 + kq * 32 + g * 8);
          #pragma unroll
          for (int i = 0; i < 2; i++)
            acc_o[i][dsub] = mfma16(pf[i], vf, acc_o[i][dsub]);
        }
      }
    }
  }

  // epilogue: normalize and store bf16 [b][l][h*64+d]
  const int b = bh >> 4, h = bh & 15;
  #pragma unroll
  for (int i = 0; i < 2; i++)
    #pragma unroll
    for (int r = 0; r < 4; r++) {
      const int qrow = q0 + wq + i * 16 + g * 4 + r;
      const float inv = 1.f / l_run[i][r];
      #pragma unroll
      for (int dsub = 0; dsub < 4; dsub++) {
        const int d = dsub * 16 + l15;
        Ob[((size_t)b * SEQ_LEN + qrow) * E_DIM + h * H_DIM + d] = f2bf(acc_o[i][dsub][r] * inv);
      }
    }
}

// ---------------- launcher ----------------
extern "C" void kernel_launch(void* const* d_in, const int* in_sizes, int n_in,
                              void* d_out, int out_size, void* d_ws, size_t ws_size,
                              hipStream_t stream) {
  const float* x  = (const float*)d_in[0];
  const int* mask = (const int*)d_in[1];
  const float* Wq = (const float*)d_in[2];
  const float* bq = (const float*)d_in[3];
  const float* Wk = (const float*)d_in[4];
  const float* bk = (const float*)d_in[5];
  const float* Wv = (const float*)d_in[6];
  const float* bv = (const float*)d_in[7];
  const float* Wo = (const float*)d_in[8];
  const float* bo = (const float*)d_in[9];

  char* ws = (char*)d_ws;
  // layout (bytes): needs 74 MB total
  unsigned short* xb     = (unsigned short*)(ws);                      // 16 MB, reused as Ob
  unsigned short* Wqkvt  = (unsigned short*)(ws + ((size_t)16 << 20)); //  6 MB
  unsigned short* Wot    = (unsigned short*)(ws + ((size_t)22 << 20)); //  2 MB
  unsigned short* Qb     = (unsigned short*)(ws + ((size_t)24 << 20)); // 16 MB
  unsigned short* Kb     = (unsigned short*)(ws + ((size_t)40 << 20)); // 16 MB
  unsigned short* Vtb    = (unsigned short*)(ws + ((size_t)56 << 20)); // 16 MB
  unsigned long long* mw = (unsigned long long*)(ws + ((size_t)72 << 20)); // 2 MB
  unsigned short* Ob = xb;  // x is dead after the QKV GEMM

  cast_x_kernel<<<8192, 256, 0, stream>>>(x, xb);
  transpose_w_kernel<<<dim3(32, 32, 4), dim3(32, 8), 0, stream>>>(Wq, Wk, Wv, Wo, Wqkvt, Wot);
  pack_mask_kernel<<<65536, 256, 0, stream>>>(mask, mw);
  gemm_kernel<0><<<dim3(64, 24), 256, 0, stream>>>(xb, Wqkvt, bq, bk, bv, Qb, Kb, Vtb, nullptr);
  attn_kernel<<<dim3(32, 32), 256, 0, stream>>>(Qb, Kb, Vtb, mw, Ob);
  gemm_kernel<1><<<dim3(64, 8), 256, 0, stream>>>(Ob, Wot, bo, nullptr, nullptr,
                                                  nullptr, nullptr, nullptr, (float*)d_out);
}

// Round 5
// 507.511 us; speedup vs baseline: 1.5677x; 1.5677x over previous
//
#include <hip/hip_runtime.h>
#include <stdint.h>

#define SEQ_LEN 4096
#define N_HEADS 16
#define H_DIM 64
#define E_DIM 1024
#define NBH 32            // BS * N_HEADS
#define M_TOT 8192        // BS * SEQ_LEN

typedef __attribute__((ext_vector_type(8))) short short8;
typedef __attribute__((ext_vector_type(4))) short s16x4;
typedef __attribute__((ext_vector_type(4))) float f32x4;
typedef __attribute__((ext_vector_type(4))) unsigned short u16x4;

__device__ __forceinline__ unsigned short f2bf(float f) {
  union { float f; uint32_t u; } c; c.f = f;
  uint32_t u = c.u;
  u += 0x7FFFu + ((u >> 16) & 1u);   // round-to-nearest-even
  return (unsigned short)(u >> 16);
}

__device__ __forceinline__ f32x4 mfma16(short8 a, short8 b, f32x4 c) {
  return __builtin_amdgcn_mfma_f32_16x16x32_bf16(a, b, c, 0, 0, 0);
}

__device__ __forceinline__ uint32_t cvtpk_bf16(float a, float b) {
  uint32_t r;
  asm("v_cvt_pk_bf16_f32 %0, %1, %2" : "=v"(r) : "v"(a), "v"(b));
  return r;
}

__device__ __forceinline__ float bperm_f(int srcLane, float v) {
  union { float f; int i; } c; c.f = v;
  c.i = __builtin_amdgcn_ds_bpermute(srcLane << 2, c.i);
  return c.f;
}

// ---------------- prep kernels ----------------

__global__ __launch_bounds__(256) void cast_x_kernel(const float* __restrict__ x,
                                                     unsigned short* __restrict__ xb) {
  const int i = (blockIdx.x * 256 + threadIdx.x) * 4;
  const f32x4 v = *(const f32x4*)(x + i);
  u16x4 o;
  #pragma unroll
  for (int j = 0; j < 4; j++) o[j] = f2bf(v[j]);
  *(u16x4*)(xb + i) = o;
}

// W [K][N] fp32 -> Wt [N][K] bf16 ; z selects Wq/Wk/Wv/Wo
__global__ __launch_bounds__(256) void transpose_w_kernel(
    const float* __restrict__ Wq, const float* __restrict__ Wk,
    const float* __restrict__ Wv, const float* __restrict__ Wo,
    unsigned short* __restrict__ Wqkvt, unsigned short* __restrict__ Wot) {
  __shared__ float tile[32][33];
  const int z = blockIdx.z;
  const float* src = (z == 0) ? Wq : (z == 1) ? Wk : (z == 2) ? Wv : Wo;
  unsigned short* dst = (z < 3) ? (Wqkvt + (size_t)z * E_DIM * E_DIM) : Wot;
  const int n0 = blockIdx.x * 32, k0 = blockIdx.y * 32;
  const int tx = threadIdx.x, ty = threadIdx.y;
  #pragma unroll
  for (int i = 0; i < 4; i++)
    tile[ty + i * 8][tx] = src[(size_t)(k0 + ty + i * 8) * E_DIM + n0 + tx];
  __syncthreads();
  #pragma unroll
  for (int i = 0; i < 4; i++)
    dst[(size_t)(n0 + ty + i * 8) * E_DIM + k0 + tx] = f2bf(tile[tx][ty + i * 8]);
}

// mask int32 [L][L] -> bitmask uint64 [L][L/64]
__global__ __launch_bounds__(256) void pack_mask_kernel(const int* __restrict__ mask,
                                                        unsigned long long* __restrict__ mw) {
  const int e = blockIdx.x * 256 + threadIdx.x;
  const int bit = mask[e] != 0;
  const unsigned long long bal = __ballot(bit);
  if ((threadIdx.x & 63) == 0) mw[e >> 6] = bal;
}

// ---------------- GEMM: C[m][n] = sum_k A[m][k] * Bt[n][k] (+bias) ----------------
// MODE 0: fused QKV epilogue (scatter Q (pre-scaled by 0.125*log2e), K [bh][l][d],
//         V transposed [bh][d][l], bf16)
// MODE 1: fp32 output + bias (b0)
#define LDT 40   // padded LDS row (elems) for 32-wide K tiles
#define QSCALE 0.18033688011112042f   // 0.125 * log2(e)

template<int MODE>
__global__ __launch_bounds__(256) void gemm_kernel(
    const unsigned short* __restrict__ A,
    const unsigned short* __restrict__ Bt,
    const float* __restrict__ b0, const float* __restrict__ b1, const float* __restrict__ b2,
    unsigned short* __restrict__ Qo, unsigned short* __restrict__ Ko,
    unsigned short* __restrict__ Vto, float* __restrict__ Co)
{
  __shared__ unsigned short As[128 * LDT];
  __shared__ unsigned short Bs[128 * LDT];
  const int tid = threadIdx.x;
  const int lane = tid & 63, wid = tid >> 6;
  const int l15 = lane & 15, g = lane >> 4;
  const int bm = blockIdx.x * 128, bn = blockIdx.y * 128;
  const int wm = (wid >> 1) * 64, wn = (wid & 1) * 64;

  const int srow = tid >> 2, scol = (tid & 3) * 8;
  const unsigned short* ap0 = A  + (size_t)(bm + srow) * E_DIM + scol;
  const unsigned short* ap1 = ap0 + (size_t)64 * E_DIM;
  const unsigned short* bp0 = Bt + (size_t)(bn + srow) * E_DIM + scol;
  const unsigned short* bp1 = bp0 + (size_t)64 * E_DIM;
  unsigned short* aw0 = As + srow * LDT + scol;
  unsigned short* aw1 = aw0 + 64 * LDT;
  unsigned short* bw0 = Bs + srow * LDT + scol;
  unsigned short* bw1 = bw0 + 64 * LDT;

  f32x4 acc[4][4] = {};

  for (int k0 = 0; k0 < E_DIM; k0 += 32) {
    const short8 ra0 = *(const short8*)(ap0 + k0);
    const short8 ra1 = *(const short8*)(ap1 + k0);
    const short8 rb0 = *(const short8*)(bp0 + k0);
    const short8 rb1 = *(const short8*)(bp1 + k0);
    __syncthreads();
    *(short8*)aw0 = ra0;  *(short8*)aw1 = ra1;
    *(short8*)bw0 = rb0;  *(short8*)bw1 = rb1;
    __syncthreads();
    short8 af[4], bf[4];
    #pragma unroll
    for (int i = 0; i < 4; i++)
      af[i] = *(const short8*)(As + (wm + i * 16 + l15) * LDT + g * 8);
    #pragma unroll
    for (int j = 0; j < 4; j++)
      bf[j] = *(const short8*)(Bs + (wn + j * 16 + l15) * LDT + g * 8);
    #pragma unroll
    for (int i = 0; i < 4; i++)
      #pragma unroll
      for (int j = 0; j < 4; j++)
        acc[i][j] = mfma16(af[i], bf[j], acc[i][j]);
  }

  #pragma unroll
  for (int i = 0; i < 4; i++) {
    #pragma unroll
    for (int j = 0; j < 4; j++) {
      const int n  = bn + wn + j * 16 + l15;
      const int m0 = bm + wm + i * 16 + g * 4;
      if (MODE == 1) {
        const float bias = b0[n];
        #pragma unroll
        for (int r = 0; r < 4; r++)
          Co[(size_t)(m0 + r) * E_DIM + n] = acc[i][j][r] + bias;
      } else {
        const int sec = n >> 10, nn = n & 1023;
        const int h = nn >> 6, d = nn & 63;
        const float bias = (sec == 0 ? b0 : sec == 1 ? b1 : b2)[nn];
        if (sec == 2) {
          u16x4 vv;
          #pragma unroll
          for (int r = 0; r < 4; r++) vv[r] = f2bf(acc[i][j][r] + bias);
          const int b = m0 >> 12, l0 = m0 & 4095;
          *(u16x4*)(Vto + ((size_t)(b * N_HEADS + h) * H_DIM + d) * SEQ_LEN + l0) = vv;
        } else {
          unsigned short* dst = (sec == 0) ? Qo : Ko;
          const float scl = (sec == 0) ? QSCALE : 1.0f;
          #pragma unroll
          for (int r = 0; r < 4; r++) {
            const int m = m0 + r;
            const int b = m >> 12, l = m & 4095;
            dst[((size_t)(b * N_HEADS + h) * SEQ_LEN + l) * H_DIM + d] =
                f2bf((acc[i][j][r] + bias) * scl);
          }
        }
      }
    }
  }
}

// ---------------- flash attention (swapped QK^T, in-register softmax) ----------------
// grid (SEQ_LEN/128, NBH), 256 threads (4 waves x 32 q-rows)
// Swapped mfma(K,Q): S^T tile with q on l15, key on g*4+r -> row stats are in-lane
// + 2 shfl hops. P never leaves registers: V LDS is key-permuted so the PV
// A-fragment (slot g*8+s <-> key 16*(s>>2)+4g+(s&3)) is an in-lane cvt_pk repack.
#define LDK 72    // Ks padded row (elems), 64 cols  (8 lanes/bank-group: optimal)
#define LDV 136   // Vs padded row (elems), 128 slots
#define DEFER_THR 8.0f   // exp2-domain defer-max threshold (p <= 2^8)

__global__ __launch_bounds__(256, 2) void attn_kernel(
    const unsigned short* __restrict__ Qg, const unsigned short* __restrict__ Kg,
    const unsigned short* __restrict__ Vg, const unsigned long long* __restrict__ mw,
    unsigned short* __restrict__ Ob)
{
  __shared__ unsigned short Ks[128 * LDK];   // 18432 B
  __shared__ unsigned short Vs[64 * LDV];    // 17408 B (key-permuted V^T tile)
  const int tid = threadIdx.x, lane = tid & 63, wid = tid >> 6;
  const int l15 = lane & 15, g = lane >> 4;
  const int q0 = blockIdx.x * 128, bh = blockIdx.y;
  const unsigned short* Qp = Qg + ((size_t)bh * SEQ_LEN + q0 + wid * 32) * H_DIM;
  const unsigned short* Kp = Kg + (size_t)bh * SEQ_LEN * H_DIM;
  const unsigned short* Vp = Vg + (size_t)bh * H_DIM * SEQ_LEN;

  // Q fragments (b-operand: rows q on l15) straight from global, once
  short8 qf[2][2];
  #pragma unroll
  for (int i = 0; i < 2; i++)
    #pragma unroll
    for (int h = 0; h < 2; h++)
      qf[i][h] = *(const short8*)(Qp + (i * 16 + l15) * H_DIM + h * 32 + g * 8);

  float m_run[2] = {-1e30f, -1e30f}, l_run[2] = {0.f, 0.f};
  f32x4 acc[2][4] = {};

  for (int kt = 0; kt < SEQ_LEN / 128; kt++) {
    // ---- stage K [128][64] and key-permuted V^T [64][128] ----
    short8 rk[4], rv[4];
    #pragma unroll
    for (int it = 0; it < 4; it++) {
      const int idx = it * 256 + tid;
      rk[it] = *(const short8*)(Kp + (size_t)(kt * 128 + (idx >> 3)) * H_DIM + (idx & 7) * 8);
      rv[it] = *(const short8*)(Vp + (size_t)(idx >> 4) * SEQ_LEN + kt * 128 + (idx & 15) * 8);
    }
    __syncthreads();
    #pragma unroll
    for (int it = 0; it < 4; it++) {
      const int idx = it * 256 + tid;
      *(short8*)(Ks + (idx >> 3) * LDK + (idx & 7) * 8) = rk[it];
      // permuted V write: global keys c..c+7 -> slots base1..+3 and base1+8..+11
      const int d = idx >> 4, c = (idx & 15) * 8;
      const int base1 = (c >> 5) * 32 + ((c & 15) >> 2) * 8 + ((c >> 4) & 1) * 4;
      s16x4 lo, hi;
      #pragma unroll
      for (int e = 0; e < 4; e++) { lo[e] = rv[it][e]; hi[e] = rv[it][e + 4]; }
      *(s16x4*)(Vs + d * LDV + base1) = lo;
      *(s16x4*)(Vs + d * LDV + base1 + 8) = hi;
    }
    __syncthreads();

    // ---- S^T = K Q^T : s[i][j] lane holds S[q=i*16+l15][key=j*16+g*4+r] ----
    f32x4 s[2][8];
    #pragma unroll
    for (int j = 0; j < 8; j++) {
      const short8 kf0 = *(const short8*)(Ks + (j * 16 + l15) * LDK + g * 8);
      const short8 kf1 = *(const short8*)(Ks + (j * 16 + l15) * LDK + 32 + g * 8);
      #pragma unroll
      for (int i = 0; i < 2; i++) {
        f32x4 z = {0.f, 0.f, 0.f, 0.f};
        z = mfma16(kf0, qf[i][0], z);
        s[i][j] = mfma16(kf1, qf[i][1], z);
      }
    }

    // mask words for this lane's two q-rows, pre-shifted by 4g
    unsigned long long wsh0[2], wsh1[2];
    #pragma unroll
    for (int i = 0; i < 2; i++) {
      const unsigned long long* mp =
          mw + (size_t)(q0 + wid * 32 + i * 16 + l15) * (SEQ_LEN / 64) + kt * 2;
      wsh0[i] = mp[0] >> (g * 4);
      wsh1[i] = mp[1] >> (g * 4);
    }

    // ---- tile max (raw scores; masking done post-exp) ----
    float tm[2];
    #pragma unroll
    for (int i = 0; i < 2; i++) {
      f32x4 t4 = s[i][0];
      #pragma unroll
      for (int j = 1; j < 8; j++)
        #pragma unroll
        for (int r = 0; r < 4; r++) t4[r] = fmaxf(t4[r], s[i][j][r]);
      float t = fmaxf(fmaxf(t4[0], t4[1]), fmaxf(t4[2], t4[3]));
      t = fmaxf(t, __shfl_xor(t, 16));
      t = fmaxf(t, __shfl_xor(t, 32));
      tm[i] = t;
    }

    // ---- defer-max rescale (rare) ----
    const int need = (tm[0] > m_run[0] + DEFER_THR) | (tm[1] > m_run[1] + DEFER_THR);
    if (__any(need)) {
      #pragma unroll
      for (int i = 0; i < 2; i++) {
        const float mn = fmaxf(m_run[i], tm[i]);
        const float corr = __builtin_amdgcn_exp2f(m_run[i] - mn);
        m_run[i] = mn;
        l_run[i] *= corr;
        float cR[4];
        #pragma unroll
        for (int r = 0; r < 4; r++) cR[r] = bperm_f(g * 4 + r, corr);
        #pragma unroll
        for (int dsub = 0; dsub < 4; dsub++)
          #pragma unroll
          for (int r = 0; r < 4; r++) acc[i][dsub][r] *= cR[r];
      }
    }

    // ---- p = exp2(s - m), zero masked, row-sum ----
    #pragma unroll
    for (int i = 0; i < 2; i++) {
      f32x4 sum4 = {0.f, 0.f, 0.f, 0.f};
      #pragma unroll
      for (int j = 0; j < 8; j++) {
        const unsigned long long w = (j < 4) ? wsh0[i] : wsh1[i];
        #pragma unroll
        for (int r = 0; r < 4; r++) {
          const float p = __builtin_amdgcn_exp2f(s[i][j][r] - m_run[i]);
          const uint32_t bit = (uint32_t)(w >> ((j & 3) * 16 + r)) & 1u;
          s[i][j][r] = __uint_as_float(__float_as_uint(p) & (bit - 1u));
        }
        #pragma unroll
        for (int r = 0; r < 4; r++) sum4[r] += s[i][j][r];
      }
      float rs = (sum4[0] + sum4[1]) + (sum4[2] + sum4[3]);
      rs += __shfl_xor(rs, 16);
      rs += __shfl_xor(rs, 32);
      l_run[i] += rs;
    }

    // ---- PV: in-lane repack to bf16 A-fragments, permuted V B-fragments ----
    #pragma unroll
    for (int kk = 0; kk < 4; kk++) {
      union { short8 s8; uint32_t u[4]; } pa0, pa1;
      pa0.u[0] = cvtpk_bf16(s[0][2 * kk][0], s[0][2 * kk][1]);
      pa0.u[1] = cvtpk_bf16(s[0][2 * kk][2], s[0][2 * kk][3]);
      pa0.u[2] = cvtpk_bf16(s[0][2 * kk + 1][0], s[0][2 * kk + 1][1]);
      pa0.u[3] = cvtpk_bf16(s[0][2 * kk + 1][2], s[0][2 * kk + 1][3]);
      pa1.u[0] = cvtpk_bf16(s[1][2 * kk][0], s[1][2 * kk][1]);
      pa1.u[1] = cvtpk_bf16(s[1][2 * kk][2], s[1][2 * kk][3]);
      pa1.u[2] = cvtpk_bf16(s[1][2 * kk + 1][0], s[1][2 * kk + 1][1]);
      pa1.u[3] = cvtpk_bf16(s[1][2 * kk + 1][2], s[1][2 * kk + 1][3]);
      #pragma unroll
      for (int dsub = 0; dsub < 4; dsub++) {
        const short8 vf = *(const short8*)(Vs + (dsub * 16 + l15) * LDV + kk * 32 + g * 8);
        acc[0][dsub] = mfma16(pa0.s8, vf, acc[0][dsub]);
        acc[1][dsub] = mfma16(pa1.s8, vf, acc[1][dsub]);
      }
    }
  }

  // ---- epilogue: pull l for accumulator rows, normalize, store bf16 ----
  const int b = bh >> 4, h = bh & 15;
  #pragma unroll
  for (int i = 0; i < 2; i++) {
    float inv[4];
    #pragma unroll
    for (int r = 0; r < 4; r++) inv[r] = 1.f / bperm_f(g * 4 + r, l_run[i]);
    #pragma unroll
    for (int dsub = 0; dsub < 4; dsub++)
      #pragma unroll
      for (int r = 0; r < 4; r++) {
        const int qrow = q0 + wid * 32 + i * 16 + g * 4 + r;
        Ob[((size_t)b * SEQ_LEN + qrow) * E_DIM + h * H_DIM + dsub * 16 + l15] =
            f2bf(acc[i][dsub][r] * inv[r]);
      }
  }
}

// ---------------- launcher ----------------
extern "C" void kernel_launch(void* const* d_in, const int* in_sizes, int n_in,
                              void* d_out, int out_size, void* d_ws, size_t ws_size,
                              hipStream_t stream) {
  const float* x  = (const float*)d_in[0];
  const int* mask = (const int*)d_in[1];
  const float* Wq = (const float*)d_in[2];
  const float* bq = (const float*)d_in[3];
  const float* Wk = (const float*)d_in[4];
  const float* bk = (const float*)d_in[5];
  const float* Wv = (const float*)d_in[6];
  const float* bv = (const float*)d_in[7];
  const float* Wo = (const float*)d_in[8];
  const float* bo = (const float*)d_in[9];

  char* ws = (char*)d_ws;
  // layout (bytes): needs 74 MB total
  unsigned short* xb     = (unsigned short*)(ws);                      // 16 MB, reused as Ob
  unsigned short* Wqkvt  = (unsigned short*)(ws + ((size_t)16 << 20)); //  6 MB
  unsigned short* Wot    = (unsigned short*)(ws + ((size_t)22 << 20)); //  2 MB
  unsigned short* Qb     = (unsigned short*)(ws + ((size_t)24 << 20)); // 16 MB
  unsigned short* Kb     = (unsigned short*)(ws + ((size_t)40 << 20)); // 16 MB
  unsigned short* Vtb    = (unsigned short*)(ws + ((size_t)56 << 20)); // 16 MB
  unsigned long long* mw = (unsigned long long*)(ws + ((size_t)72 << 20)); // 2 MB
  unsigned short* Ob = xb;  // x is dead after the QKV GEMM

  cast_x_kernel<<<8192, 256, 0, stream>>>(x, xb);
  transpose_w_kernel<<<dim3(32, 32, 4), dim3(32, 8), 0, stream>>>(Wq, Wk, Wv, Wo, Wqkvt, Wot);
  pack_mask_kernel<<<65536, 256, 0, stream>>>(mask, mw);
  gemm_kernel<0><<<dim3(64, 24), 256, 0, stream>>>(xb, Wqkvt, bq, bk, bv, Qb, Kb, Vtb, nullptr);
  attn_kernel<<<dim3(32, 32), 256, 0, stream>>>(Qb, Kb, Vtb, mw, Ob);
  gemm_kernel<1><<<dim3(64, 8), 256, 0, stream>>>(Ob, Wot, bo, nullptr, nullptr,
                                                  nullptr, nullptr, nullptr, (float*)d_out);
}

// Round 6
// 473.786 us; speedup vs baseline: 1.6793x; 1.0712x over previous
//
#include <hip/hip_runtime.h>
#include <stdint.h>

#define SEQ_LEN 4096
#define N_HEADS 16
#define H_DIM 64
#define E_DIM 1024
#define NBH 32            // BS * N_HEADS
#define M_TOT 8192        // BS * SEQ_LEN
#define KTILES (SEQ_LEN / 128)

typedef __attribute__((ext_vector_type(8))) short short8;
typedef __attribute__((ext_vector_type(4))) short s16x4;
typedef __attribute__((ext_vector_type(4))) float f32x4;
typedef __attribute__((ext_vector_type(4))) unsigned short u16x4;

__device__ __forceinline__ unsigned short f2bf(float f) {
  union { float f; uint32_t u; } c; c.f = f;
  uint32_t u = c.u;
  u += 0x7FFFu + ((u >> 16) & 1u);   // round-to-nearest-even
  return (unsigned short)(u >> 16);
}

__device__ __forceinline__ f32x4 mfma16(short8 a, short8 b, f32x4 c) {
  return __builtin_amdgcn_mfma_f32_16x16x32_bf16(a, b, c, 0, 0, 0);
}

__device__ __forceinline__ uint32_t cvtpk_bf16(float a, float b) {
  uint32_t r;
  asm("v_cvt_pk_bf16_f32 %0, %1, %2" : "=v"(r) : "v"(a), "v"(b));
  return r;
}

__device__ __forceinline__ float bperm_f(int srcLane, float v) {
  union { float f; int i; } c; c.f = v;
  c.i = __builtin_amdgcn_ds_bpermute(srcLane << 2, c.i);
  return c.f;
}

// ---------------- prep kernels ----------------

__global__ __launch_bounds__(256) void cast_x_kernel(const float* __restrict__ x,
                                                     unsigned short* __restrict__ xb) {
  const int i = (blockIdx.x * 256 + threadIdx.x) * 4;
  const f32x4 v = *(const f32x4*)(x + i);
  u16x4 o;
  #pragma unroll
  for (int j = 0; j < 4; j++) o[j] = f2bf(v[j]);
  *(u16x4*)(xb + i) = o;
}

// W [K][N] fp32 -> Wt [N][K] bf16 ; z selects Wq/Wk/Wv/Wo
__global__ __launch_bounds__(256) void transpose_w_kernel(
    const float* __restrict__ Wq, const float* __restrict__ Wk,
    const float* __restrict__ Wv, const float* __restrict__ Wo,
    unsigned short* __restrict__ Wqkvt, unsigned short* __restrict__ Wot) {
  __shared__ float tile[32][33];
  const int z = blockIdx.z;
  const float* src = (z == 0) ? Wq : (z == 1) ? Wk : (z == 2) ? Wv : Wo;
  unsigned short* dst = (z < 3) ? (Wqkvt + (size_t)z * E_DIM * E_DIM) : Wot;
  const int n0 = blockIdx.x * 32, k0 = blockIdx.y * 32;
  const int tx = threadIdx.x, ty = threadIdx.y;
  #pragma unroll
  for (int i = 0; i < 4; i++)
    tile[ty + i * 8][tx] = src[(size_t)(k0 + ty + i * 8) * E_DIM + n0 + tx];
  __syncthreads();
  #pragma unroll
  for (int i = 0; i < 4; i++)
    dst[(size_t)(n0 + ty + i * 8) * E_DIM + k0 + tx] = f2bf(tile[tx][ty + i * 8]);
}

// mask int32 [L][L] -> bitmask uint64 [L][L/64]
__global__ __launch_bounds__(256) void pack_mask_kernel(const int* __restrict__ mask,
                                                        unsigned long long* __restrict__ mw) {
  const int e = blockIdx.x * 256 + threadIdx.x;
  const int bit = mask[e] != 0;
  const unsigned long long bal = __ballot(bit);
  if ((threadIdx.x & 63) == 0) mw[e >> 6] = bal;
}

// ---------------- GEMM: C[m][n] = sum_k A[m][k] * Bt[n][k] (+bias) ----------------
// Double-buffered LDS, 1 barrier per K-step (loads issued early, writes late).
// MODE 0: fused QKV epilogue (scatter Q (pre-scaled by 0.125*log2e), K [bh][l][d],
//         V transposed [bh][d][l], bf16)
// MODE 1: fp32 output + bias (b0)
#define LDT 40   // padded LDS row (elems) for 32-wide K tiles
#define QSCALE 0.18033688011112042f   // 0.125 * log2(e)

template<int MODE>
__global__ __launch_bounds__(256) void gemm_kernel(
    const unsigned short* __restrict__ A,
    const unsigned short* __restrict__ Bt,
    const float* __restrict__ b0, const float* __restrict__ b1, const float* __restrict__ b2,
    unsigned short* __restrict__ Qo, unsigned short* __restrict__ Ko,
    unsigned short* __restrict__ Vto, float* __restrict__ Co)
{
  __shared__ unsigned short As[2][128 * LDT];
  __shared__ unsigned short Bs[2][128 * LDT];
  const int tid = threadIdx.x;
  const int lane = tid & 63, wid = tid >> 6;
  const int l15 = lane & 15, g = lane >> 4;
  const int bm = blockIdx.x * 128, bn = blockIdx.y * 128;
  const int wm = (wid >> 1) * 64, wn = (wid & 1) * 64;

  const int srow = tid >> 2, scol = (tid & 3) * 8;
  const unsigned short* ap0 = A  + (size_t)(bm + srow) * E_DIM + scol;
  const unsigned short* ap1 = ap0 + (size_t)64 * E_DIM;
  const unsigned short* bp0 = Bt + (size_t)(bn + srow) * E_DIM + scol;
  const unsigned short* bp1 = bp0 + (size_t)64 * E_DIM;
  const int w0 = srow * LDT + scol, w1 = w0 + 64 * LDT;

  f32x4 acc[4][4] = {};

  // prologue: stage k0 = 0
  short8 ra0 = *(const short8*)(ap0);
  short8 ra1 = *(const short8*)(ap1);
  short8 rb0 = *(const short8*)(bp0);
  short8 rb1 = *(const short8*)(bp1);
  *(short8*)(&As[0][0] + w0) = ra0;  *(short8*)(&As[0][0] + w1) = ra1;
  *(short8*)(&Bs[0][0] + w0) = rb0;  *(short8*)(&Bs[0][0] + w1) = rb1;
  __syncthreads();

  int cur = 0;
  for (int k0 = 0; k0 < E_DIM; k0 += 32) {
    const bool hasn = (k0 + 32) < E_DIM;
    if (hasn) {
      ra0 = *(const short8*)(ap0 + k0 + 32);
      ra1 = *(const short8*)(ap1 + k0 + 32);
      rb0 = *(const short8*)(bp0 + k0 + 32);
      rb1 = *(const short8*)(bp1 + k0 + 32);
    }
    const unsigned short* AsC = &As[cur][0];
    const unsigned short* BsC = &Bs[cur][0];
    short8 af[4], bf[4];
    #pragma unroll
    for (int i = 0; i < 4; i++)
      af[i] = *(const short8*)(AsC + (wm + i * 16 + l15) * LDT + g * 8);
    #pragma unroll
    for (int j = 0; j < 4; j++)
      bf[j] = *(const short8*)(BsC + (wn + j * 16 + l15) * LDT + g * 8);
    #pragma unroll
    for (int i = 0; i < 4; i++)
      #pragma unroll
      for (int j = 0; j < 4; j++)
        acc[i][j] = mfma16(af[i], bf[j], acc[i][j]);
    if (hasn) {
      unsigned short* AsN = &As[cur ^ 1][0];
      unsigned short* BsN = &Bs[cur ^ 1][0];
      *(short8*)(AsN + w0) = ra0;  *(short8*)(AsN + w1) = ra1;
      *(short8*)(BsN + w0) = rb0;  *(short8*)(BsN + w1) = rb1;
    }
    __syncthreads();
    cur ^= 1;
  }

  #pragma unroll
  for (int i = 0; i < 4; i++) {
    #pragma unroll
    for (int j = 0; j < 4; j++) {
      const int n  = bn + wn + j * 16 + l15;
      const int m0 = bm + wm + i * 16 + g * 4;
      if (MODE == 1) {
        const float bias = b0[n];
        #pragma unroll
        for (int r = 0; r < 4; r++)
          Co[(size_t)(m0 + r) * E_DIM + n] = acc[i][j][r] + bias;
      } else {
        const int sec = n >> 10, nn = n & 1023;
        const int h = nn >> 6, d = nn & 63;
        const float bias = (sec == 0 ? b0 : sec == 1 ? b1 : b2)[nn];
        if (sec == 2) {
          u16x4 vv;
          #pragma unroll
          for (int r = 0; r < 4; r++) vv[r] = f2bf(acc[i][j][r] + bias);
          const int b = m0 >> 12, l0 = m0 & 4095;
          *(u16x4*)(Vto + ((size_t)(b * N_HEADS + h) * H_DIM + d) * SEQ_LEN + l0) = vv;
        } else {
          unsigned short* dst = (sec == 0) ? Qo : Ko;
          const float scl = (sec == 0) ? QSCALE : 1.0f;
          #pragma unroll
          for (int r = 0; r < 4; r++) {
            const int m = m0 + r;
            const int b = m >> 12, l = m & 4095;
            dst[((size_t)(b * N_HEADS + h) * SEQ_LEN + l) * H_DIM + d] =
                f2bf((acc[i][j][r] + bias) * scl);
          }
        }
      }
    }
  }
}

// ---------------- flash attention (swapped QK^T, in-register softmax) ----------------
// grid (32, 32) -> XCD-swizzled (bh, q-block); 256 threads (4 waves x 32 q-rows).
// Double-buffered K/V LDS, ONE barrier per tile; loads issued at top, LDS writes
// interleaved mid-compute (K after QK^T, V after exp).  l accumulated via
// ones-column MFMA (no per-tile sum pass, no epilogue bperm).  m_run init 4.0
// so defer-max rescale statistically never fires (correct path kept).
#define LDK 72    // Ks padded row (elems), 64 cols
#define LDV 136   // Vs padded row (elems), 128 slots
#define DEFER_THR 8.0f   // exp2-domain defer-max threshold

__global__ __launch_bounds__(256, 2) void attn_kernel(
    const unsigned short* __restrict__ Qg, const unsigned short* __restrict__ Kg,
    const unsigned short* __restrict__ Vg, const unsigned long long* __restrict__ mw,
    unsigned short* __restrict__ Ob)
{
  __shared__ unsigned short Ks[2][128 * LDK];   // 36864 B
  __shared__ unsigned short Vs[2][64 * LDV];    // 34816 B (key-permuted V^T tiles)
  const int tid = threadIdx.x, lane = tid & 63, wid = tid >> 6;
  const int l15 = lane & 15, g = lane >> 4;
  // XCD swizzle: consecutive dispatch IDs round-robin XCDs; give each XCD a
  // contiguous run of bh so its 4 heads' K/V (4 MB) live in its private L2.
  const int p = blockIdx.y * 32 + blockIdx.x;
  const int L = (p & 7) * 128 + (p >> 3);
  const int q0 = (L & 31) * 128, bh = L >> 5;
  const unsigned short* Qp = Qg + ((size_t)bh * SEQ_LEN + q0 + wid * 32) * H_DIM;
  const unsigned short* Kp = Kg + (size_t)bh * SEQ_LEN * H_DIM;
  const unsigned short* Vp = Vg + (size_t)bh * H_DIM * SEQ_LEN;

  // Q fragments (b-operand: rows q on l15) straight from global, once
  short8 qf[2][2];
  #pragma unroll
  for (int i = 0; i < 2; i++)
    #pragma unroll
    for (int h = 0; h < 2; h++)
      qf[i][h] = *(const short8*)(Qp + (i * 16 + l15) * H_DIM + h * 32 + g * 8);

  // hoisted lane-constant staging addresses
  const unsigned short* kg[4];
  const unsigned short* vg[4];
  int kw[4], vw[4];
  #pragma unroll
  for (int it = 0; it < 4; it++) {
    const int idx = it * 256 + tid;
    const int rk_ = idx >> 3, ck_ = (idx & 7) * 8;
    const int rv_ = idx >> 4, cv_ = (idx & 15) * 8;
    const int b1 = (cv_ >> 5) * 32 + ((cv_ & 15) >> 2) * 8 + ((cv_ >> 4) & 1) * 4;
    kg[it] = Kp + (size_t)rk_ * H_DIM + ck_;
    vg[it] = Vp + (size_t)rv_ * SEQ_LEN + cv_;
    kw[it] = rk_ * LDK + ck_;
    vw[it] = rv_ * LDV + b1;
  }
  const unsigned long long* mbase[2];
  #pragma unroll
  for (int i = 0; i < 2; i++)
    mbase[i] = mw + (size_t)(q0 + wid * 32 + i * 16 + l15) * (SEQ_LEN / 64);

  float m_run[2] = {4.0f, 4.0f};
  f32x4 acc[2][4] = {};
  f32x4 accl[2] = {};
  const short8 vone = {(short)0x3F80, (short)0x3F80, (short)0x3F80, (short)0x3F80,
                       (short)0x3F80, (short)0x3F80, (short)0x3F80, (short)0x3F80};

  // prologue: stage tile 0 into buf 0
  short8 rk[4], rv[4];
  #pragma unroll
  for (int it = 0; it < 4; it++) {
    rk[it] = *(const short8*)(kg[it]);
    rv[it] = *(const short8*)(vg[it]);
  }
  #pragma unroll
  for (int it = 0; it < 4; it++) {
    *(short8*)(&Ks[0][0] + kw[it]) = rk[it];
    s16x4 lo, hi;
    #pragma unroll
    for (int e = 0; e < 4; e++) { lo[e] = rv[it][e]; hi[e] = rv[it][e + 4]; }
    *(s16x4*)(&Vs[0][0] + vw[it]) = lo;
    *(s16x4*)(&Vs[0][0] + vw[it] + 8) = hi;
  }
  __syncthreads();

  int cur = 0;
  for (int kt = 0; kt < KTILES; kt++) {
    const bool hasn = (kt + 1) < KTILES;
    if (hasn) {
      #pragma unroll
      for (int it = 0; it < 4; it++) {
        rk[it] = *(const short8*)(kg[it] + (size_t)(kt + 1) * 128 * H_DIM);
        rv[it] = *(const short8*)(vg[it] + (kt + 1) * 128);
      }
    }
    // mask words for this tile, pre-shifted by 4g
    unsigned long long wA[2], wB[2];
    #pragma unroll
    for (int i = 0; i < 2; i++) {
      const unsigned long long* mp = mbase[i] + kt * 2;
      wA[i] = mp[0] >> (g * 4);
      wB[i] = mp[1] >> (g * 4);
    }

    const unsigned short* KsC = &Ks[cur][0];
    const unsigned short* VsC = &Vs[cur][0];
    unsigned short* KsN = &Ks[cur ^ 1][0];
    unsigned short* VsN = &Vs[cur ^ 1][0];

    // ---- S^T = K Q^T : s[i][j] lane holds S[q=i*16+l15][key=j*16+g*4+r] ----
    f32x4 s[2][8];
    #pragma unroll
    for (int j = 0; j < 8; j++) {
      const short8 kf0 = *(const short8*)(KsC + (j * 16 + l15) * LDK + g * 8);
      const short8 kf1 = *(const short8*)(KsC + (j * 16 + l15) * LDK + 32 + g * 8);
      #pragma unroll
      for (int i = 0; i < 2; i++) {
        f32x4 z = {0.f, 0.f, 0.f, 0.f};
        z = mfma16(kf0, qf[i][0], z);
        s[i][j] = mfma16(kf1, qf[i][1], z);
      }
    }

    // write next K tile (buf^1 is dead this phase; frees rk)
    if (hasn) {
      #pragma unroll
      for (int it = 0; it < 4; it++) *(short8*)(KsN + kw[it]) = rk[it];
    }

    // ---- tile max (raw scores), v_max3-friendly trees ----
    float tm[2];
    #pragma unroll
    for (int i = 0; i < 2; i++) {
      f32x4 t4;
      #pragma unroll
      for (int r = 0; r < 4; r++) {
        const float a = fmaxf(fmaxf(s[i][0][r], s[i][1][r]), s[i][2][r]);
        const float b = fmaxf(fmaxf(s[i][3][r], s[i][4][r]), s[i][5][r]);
        const float c = fmaxf(fmaxf(a, s[i][6][r]), s[i][7][r]);
        t4[r] = fmaxf(b, c);
      }
      float t = fmaxf(fmaxf(t4[0], t4[1]), fmaxf(t4[2], t4[3]));
      t = fmaxf(t, __shfl_xor(t, 16));
      t = fmaxf(t, __shfl_xor(t, 32));
      tm[i] = t;
    }

    // ---- defer-max rescale (statistically never with m_init=4) ----
    if (__any((tm[0] > m_run[0] + DEFER_THR) | (tm[1] > m_run[1] + DEFER_THR))) {
      #pragma unroll
      for (int i = 0; i < 2; i++) {
        const float mn = fmaxf(m_run[i], tm[i]);
        const float corr = __builtin_amdgcn_exp2f(m_run[i] - mn);
        m_run[i] = mn;
        float cR[4];
        #pragma unroll
        for (int r = 0; r < 4; r++) cR[r] = bperm_f(g * 4 + r, corr);
        #pragma unroll
        for (int r = 0; r < 4; r++) accl[i][r] *= cR[r];
        #pragma unroll
        for (int d = 0; d < 4; d++)
          #pragma unroll
          for (int r = 0; r < 4; r++) acc[i][d][r] *= cR[r];
      }
    }

    // ---- p = exp2(s - m), zero masked (bfe + and-with-(bit-1)) ----
    #pragma unroll
    for (int i = 0; i < 2; i++) {
      const uint32_t a0 = (uint32_t)wA[i], a1 = (uint32_t)(wA[i] >> 32);
      const uint32_t b0 = (uint32_t)wB[i], b1 = (uint32_t)(wB[i] >> 32);
      #pragma unroll
      for (int j = 0; j < 8; j++) {
        #pragma unroll
        for (int r = 0; r < 4; r++) {
          const int idx = (j & 3) * 16 + r;
          const uint32_t word = (j < 4) ? ((idx < 32) ? a0 : a1)
                                        : ((idx < 32) ? b0 : b1);
          const uint32_t bit = (word >> (idx & 31)) & 1u;
          const float pf = __builtin_amdgcn_exp2f(s[i][j][r] - m_run[i]);
          s[i][j][r] = __uint_as_float(__float_as_uint(pf) & (bit - 1u));
        }
      }
    }

    // write next V tile (frees rv)
    if (hasn) {
      #pragma unroll
      for (int it = 0; it < 4; it++) {
        s16x4 lo, hi;
        #pragma unroll
        for (int e = 0; e < 4; e++) { lo[e] = rv[it][e]; hi[e] = rv[it][e + 4]; }
        *(s16x4*)(VsN + vw[it]) = lo;
        *(s16x4*)(VsN + vw[it] + 8) = hi;
      }
    }

    // ---- PV + ones-column l: in-lane cvt_pk repack, permuted V B-fragments ----
    #pragma unroll
    for (int kk = 0; kk < 4; kk++) {
      union { short8 s8; uint32_t u[4]; } pa0, pa1;
      pa0.u[0] = cvtpk_bf16(s[0][2 * kk][0], s[0][2 * kk][1]);
      pa0.u[1] = cvtpk_bf16(s[0][2 * kk][2], s[0][2 * kk][3]);
      pa0.u[2] = cvtpk_bf16(s[0][2 * kk + 1][0], s[0][2 * kk + 1][1]);
      pa0.u[3] = cvtpk_bf16(s[0][2 * kk + 1][2], s[0][2 * kk + 1][3]);
      pa1.u[0] = cvtpk_bf16(s[1][2 * kk][0], s[1][2 * kk][1]);
      pa1.u[1] = cvtpk_bf16(s[1][2 * kk][2], s[1][2 * kk][3]);
      pa1.u[2] = cvtpk_bf16(s[1][2 * kk + 1][0], s[1][2 * kk + 1][1]);
      pa1.u[3] = cvtpk_bf16(s[1][2 * kk + 1][2], s[1][2 * kk + 1][3]);
      accl[0] = mfma16(pa0.s8, vone, accl[0]);
      accl[1] = mfma16(pa1.s8, vone, accl[1]);
      #pragma unroll
      for (int dsub = 0; dsub < 4; dsub++) {
        const short8 vf = *(const short8*)(VsC + (dsub * 16 + l15) * LDV + kk * 32 + g * 8);
        acc[0][dsub] = mfma16(pa0.s8, vf, acc[0][dsub]);
        acc[1][dsub] = mfma16(pa1.s8, vf, acc[1][dsub]);
      }
    }

    __syncthreads();
    cur ^= 1;
  }

  // ---- epilogue: accl already indexed by accumulator row -> no bperm ----
  const int b = bh >> 4, h = bh & 15;
  #pragma unroll
  for (int i = 0; i < 2; i++) {
    float inv[4];
    #pragma unroll
    for (int r = 0; r < 4; r++) inv[r] = 1.f / accl[i][r];
    #pragma unroll
    for (int dsub = 0; dsub < 4; dsub++)
      #pragma unroll
      for (int r = 0; r < 4; r++) {
        const int qrow = q0 + wid * 32 + i * 16 + g * 4 + r;
        Ob[((size_t)b * SEQ_LEN + qrow) * E_DIM + h * H_DIM + dsub * 16 + l15] =
            f2bf(acc[i][dsub][r] * inv[r]);
      }
  }
}

// ---------------- launcher ----------------
extern "C" void kernel_launch(void* const* d_in, const int* in_sizes, int n_in,
                              void* d_out, int out_size, void* d_ws, size_t ws_size,
                              hipStream_t stream) {
  const float* x  = (const float*)d_in[0];
  const int* mask = (const int*)d_in[1];
  const float* Wq = (const float*)d_in[2];
  const float* bq = (const float*)d_in[3];
  const float* Wk = (const float*)d_in[4];
  const float* bk = (const float*)d_in[5];
  const float* Wv = (const float*)d_in[6];
  const float* bv = (const float*)d_in[7];
  const float* Wo = (const float*)d_in[8];
  const float* bo = (const float*)d_in[9];

  char* ws = (char*)d_ws;
  // layout (bytes): needs 74 MB total
  unsigned short* xb     = (unsigned short*)(ws);                      // 16 MB, reused as Ob
  unsigned short* Wqkvt  = (unsigned short*)(ws + ((size_t)16 << 20)); //  6 MB
  unsigned short* Wot    = (unsigned short*)(ws + ((size_t)22 << 20)); //  2 MB
  unsigned short* Qb     = (unsigned short*)(ws + ((size_t)24 << 20)); // 16 MB
  unsigned short* Kb     = (unsigned short*)(ws + ((size_t)40 << 20)); // 16 MB
  unsigned short* Vtb    = (unsigned short*)(ws + ((size_t)56 << 20)); // 16 MB
  unsigned long long* mw = (unsigned long long*)(ws + ((size_t)72 << 20)); // 2 MB
  unsigned short* Ob = xb;  // x is dead after the QKV GEMM

  cast_x_kernel<<<8192, 256, 0, stream>>>(x, xb);
  transpose_w_kernel<<<dim3(32, 32, 4), dim3(32, 8), 0, stream>>>(Wq, Wk, Wv, Wo, Wqkvt, Wot);
  pack_mask_kernel<<<65536, 256, 0, stream>>>(mask, mw);
  gemm_kernel<0><<<dim3(64, 24), 256, 0, stream>>>(xb, Wqkvt, bq, bk, bv, Qb, Kb, Vtb, nullptr);
  attn_kernel<<<dim3(32, 32), 256, 0, stream>>>(Qb, Kb, Vtb, mw, Ob);
  gemm_kernel<1><<<dim3(64, 8), 256, 0, stream>>>(Ob, Wot, bo, nullptr, nullptr,
                                                  nullptr, nullptr, nullptr, (float*)d_out);
}